// Round 19
// baseline (99.633 us; speedup 1.0000x reference)
//
#include <hip/hip_runtime.h>
#include <stdint.h>

typedef __attribute__((ext_vector_type(8))) short bf16x8;
typedef __attribute__((ext_vector_type(4))) float f32x4;
typedef __attribute__((ext_vector_type(16))) float f32x16;

#define MFMA_16x16x32(a, b, c) __builtin_amdgcn_mfma_f32_16x16x32_bf16((a), (b), (c), 0, 0, 0)
#define MFMA_32x32x16(a, b, c) __builtin_amdgcn_mfma_f32_32x32x16_bf16((a), (b), (c), 0, 0, 0)

__device__ __forceinline__ short f2bf(float f) {
  union { float f; uint32_t u; } x;
  x.f = f;
  uint32_t r = x.u + 0x7fffu + ((x.u >> 16) & 1u);
  return (short)(r >> 16);
}

__device__ __forceinline__ uint32_t cvt_pk_bf16(float lo, float hi) {
  uint32_t r;
  asm("v_cvt_pk_bf16_f32 %0, %1, %2" : "=v"(r) : "v"(lo), "v"(hi));
  return r;
}

__device__ __forceinline__ void gload_lds16(const short* g, short* l) {
  __builtin_amdgcn_global_load_lds(
      (const __attribute__((address_space(1))) void*)g,
      (__attribute__((address_space(3))) void*)l, 16, 0, 0);
}

// ---------------- merged cast f32 -> bf16 (Q-rows of w_qkv pre-scaled by 1/8) ----------------
__global__ __launch_bounds__(256) void cast_all(const float* __restrict__ x,
                                                const float* __restrict__ wq,
                                                const float* __restrict__ wo,
                                                short* __restrict__ xb,
                                                short* __restrict__ wqb,
                                                short* __restrict__ wob) {
  int i = blockIdx.x * 256 + threadIdx.x;
  const float* s;
  short* d;
  int off;
  float sc = 1.0f;
  if (i < 524288) { s = x; d = xb; off = i; }
  else if (i < 917504) {
    s = wq; d = wqb; off = i - 524288;
    if (off < 131072) sc = 0.125f;
  }
  else { s = wo; d = wob; off = i - 917504; }
  const float4* sp = (const float4*)s;
  float4 v0 = sp[(size_t)off * 2 + 0];
  float4 v1 = sp[(size_t)off * 2 + 1];
  bf16x8 o;
  o[0] = f2bf(v0.x * sc); o[1] = f2bf(v0.y * sc); o[2] = f2bf(v0.z * sc); o[3] = f2bf(v0.w * sc);
  o[4] = f2bf(v1.x * sc); o[5] = f2bf(v1.y * sc); o[6] = f2bf(v1.z * sc); o[7] = f2bf(v1.w * sc);
  *(bf16x8*)(d + (size_t)off * 8) = o;
}

// ---------------- 256x192 8-phase bf16 GEMM (C = A * B^T form), grid = 256 blocks ----------------
template <int OUT_BF16>
__global__ __launch_bounds__(512, 2) void gemm256(const short* __restrict__ A,
                                                  const short* __restrict__ B,
                                                  void* __restrict__ Cp,
                                                  int M, int N, int K, int ntN) {
  __shared__ short Al[2][2][128 * 64];
  __shared__ short Bl[2][3][64 * 64];

  const int tid = threadIdx.x;
  const int wv = tid >> 6, lane = tid & 63;
  const int wr = wv >> 2, wc = wv & 3;
  const int lrow = lane & 15, kgrp = lane >> 4;
  const int l3 = lrow & 7;
  const int ck0 = ((kgrp ^ l3)) * 8;
  const int ck1 = ((kgrp ^ l3) ^ 4) * 8;

  const int nwg = gridDim.x;
  const int orig = blockIdx.x;
  const int wg = (orig & 7) * (nwg >> 3) + (orig >> 3);
  const int by = wg / ntN, bx = wg % ntN;
  const int row0 = by * 256, col0 = bx * 192;

  const int r_ = tid >> 3;
  const int cs_ = ((tid & 7) ^ (r_ & 7)) * 8;

  const int NT = K >> 6;
  const int NI = NT >> 1;
  const int NTm1 = NT - 1;

  auto stgA = [&](int slot, int h, int j, int kt) {
    gload_lds16(A + (size_t)(row0 + h * 128 + j * 64 + r_) * K + kt * 64 + cs_,
                &Al[slot][h][j * 4096 + wv * 512]);
  };
  auto stgB = [&](int slot, int j, int kt) {
    gload_lds16(B + (size_t)(col0 + j * 64 + r_) * K + kt * 64 + cs_,
                &Bl[slot][j][wv * 512]);
  };

  f32x4 acc[8][3] = {};

  stgB(0, 0, 0); stgB(0, 1, 0); stgB(0, 2, 0);
  stgA(0, 0, 0, 0); stgA(0, 0, 1, 0); stgA(0, 1, 0, 0); stgA(0, 1, 1, 0);
  stgB(1, 0, 1); stgB(1, 1, 1); stgB(1, 2, 1);
  asm volatile("s_waitcnt vmcnt(3)" ::: "memory");
  __builtin_amdgcn_s_barrier();

  for (int i = 0; i < NI; ++i) {
    const int ktB1 = (2 * i + 1);
    const int ktP2 = (2 * i + 2 > NTm1) ? NTm1 : 2 * i + 2;
    const int ktP3 = (2 * i + 3 > NTm1) ? NTm1 : 2 * i + 3;
#pragma unroll
    for (int s = 0; s < 2; ++s) {
      bf16x8 bfr[3][2];
#pragma unroll
      for (int q = 0; q < 4; ++q) {
        if (q == 0) {
#pragma unroll
          for (int n = 0; n < 3; ++n) {
            const int row = wc * 48 + n * 16 + lrow;
            const int th = row >> 6;
            const int lr = row & 63;
            bfr[n][0] = *(const bf16x8*)(&Bl[s][th][lr * 64 + ck0]);
            bfr[n][1] = *(const bf16x8*)(&Bl[s][th][lr * 64 + ck1]);
          }
        }
        bf16x8 afr[2][2];
#pragma unroll
        for (int mm = 0; mm < 2; ++mm) {
          const int m = q * 2 + mm;
          afr[mm][0] = *(const bf16x8*)(&Al[s][wr][lrow * 64 + m * 1024 + ck0]);
          afr[mm][1] = *(const bf16x8*)(&Al[s][wr][lrow * 64 + m * 1024 + ck1]);
        }
        if (s == 0) {
          if (q == 0) { stgA(1, 0, 0, ktB1); stgA(1, 0, 1, ktB1); stgA(1, 1, 0, ktB1); stgA(1, 1, 1, ktB1); }
          else if (q == 1) { stgB(0, 0, ktP2); stgB(0, 1, ktP2); }
          else if (q == 2) { stgB(0, 2, ktP2); }
        } else {
          if (q == 0) { stgA(0, 0, 0, ktP2); stgA(0, 0, 1, ktP2); stgA(0, 1, 0, ktP2); stgA(0, 1, 1, ktP2); }
          else if (q == 1) { stgB(1, 0, ktP3); stgB(1, 1, ktP3); }
          else if (q == 2) { stgB(1, 2, ktP3); }
        }
        __builtin_amdgcn_sched_barrier(0);
        __builtin_amdgcn_s_barrier();
        asm volatile("s_waitcnt lgkmcnt(0)" ::: "memory");
        __builtin_amdgcn_sched_barrier(0);
        __builtin_amdgcn_s_setprio(1);
#pragma unroll
        for (int mm = 0; mm < 2; ++mm)
#pragma unroll
          for (int n = 0; n < 3; ++n)
#pragma unroll
            for (int kk = 0; kk < 2; ++kk)
              acc[q * 2 + mm][n] = MFMA_16x16x32(afr[mm][kk], bfr[n][kk], acc[q * 2 + mm][n]);
        __builtin_amdgcn_s_setprio(0);
        __builtin_amdgcn_sched_barrier(0);
        if (q == 3) {
          asm volatile("s_waitcnt vmcnt(3)" ::: "memory");
        }
        __builtin_amdgcn_s_barrier();
      }
    }
  }

  asm volatile("s_waitcnt vmcnt(0)" ::: "memory");

#pragma unroll
  for (int m = 0; m < 8; ++m) {
    const int grow = row0 + wr * 128 + m * 16 + kgrp * 4;
#pragma unroll
    for (int n = 0; n < 3; ++n) {
      const int gcol = col0 + wc * 48 + n * 16 + lrow;
#pragma unroll
      for (int j = 0; j < 4; ++j) {
        const size_t off = (size_t)(grow + j) * N + gcol;
        if (OUT_BF16) ((short*)Cp)[off] = f2bf(acc[m][n][j]);
        else          ((float*)Cp)[off] = acc[m][n][j];
      }
    }
  }
}

// ---------------- 128x128 bf16 GEMM (output GEMM), dbuf, race-free single barrier ----------------
// Schedule per K-step: vmcnt(0) [own tile-k loads] -> barrier [all certified, prev buf free]
// -> STAGE(next) -> compute. 2 blocks/CU.
template <int OUT_BF16>
__global__ __launch_bounds__(256, 2) void gemm_bt128(const short* __restrict__ A,
                                                     const short* __restrict__ B,
                                                     void* __restrict__ Cp,
                                                     int M, int N, int K) {
  __shared__ short As[2][128 * 64];
  __shared__ short Bs[2][128 * 64];
  const int tid = threadIdx.x;
  const int wave = tid >> 6, lane = tid & 63;
  const int wr = wave >> 1, wc = wave & 1;
  const int row0 = blockIdx.y * 128, col0 = blockIdx.x * 128;
  const int lrow = lane & 15;
  const int kgrp = lane >> 4;
  const int l3 = lrow & 7;

  const int r_ = tid >> 3;                      // 0..31
  const int cs_ = ((tid & 7) ^ (r_ & 7)) * 8;   // pre-swizzled source chunk

  const int NT = K >> 6;

  auto STG = [&](int buf, int kt) {
#pragma unroll
    for (int it = 0; it < 4; ++it)
      gload_lds16(A + (size_t)(row0 + it * 32 + r_) * K + kt * 64 + cs_,
                  &As[buf][(it * 256 + wave * 64) * 8]);
#pragma unroll
    for (int it = 0; it < 4; ++it)
      gload_lds16(B + (size_t)(col0 + it * 32 + r_) * K + kt * 64 + cs_,
                  &Bs[buf][(it * 256 + wave * 64) * 8]);
  };

  f32x4 acc[4][4] = {};

  STG(0, 0);

  for (int kt = 0; kt < NT; ++kt) {
    asm volatile("s_waitcnt vmcnt(0)" ::: "memory");  // own tile-kt loads landed
    __builtin_amdgcn_s_barrier();                     // all waves' loads landed; prev buf free
    __builtin_amdgcn_sched_barrier(0);
    const int ktn = (kt + 1 >= NT) ? NT - 1 : kt + 1;
    STG((kt + 1) & 1, ktn);
    const short* Ab = As[kt & 1];
    const short* Bb = Bs[kt & 1];
#pragma unroll
    for (int kk = 0; kk < 2; ++kk) {
      const int ck = ((kk * 4 + kgrp) ^ l3) * 8;
      bf16x8 a[4], b[4];
#pragma unroll
      for (int m = 0; m < 4; ++m)
        a[m] = *(const bf16x8*)(Ab + (wr * 64 + m * 16 + lrow) * 64 + ck);
#pragma unroll
      for (int n = 0; n < 4; ++n)
        b[n] = *(const bf16x8*)(Bb + (wc * 64 + n * 16 + lrow) * 64 + ck);
      __builtin_amdgcn_s_setprio(1);
#pragma unroll
      for (int m = 0; m < 4; ++m)
#pragma unroll
        for (int n = 0; n < 4; ++n)
          acc[m][n] = MFMA_16x16x32(a[m], b[n], acc[m][n]);
      __builtin_amdgcn_s_setprio(0);
    }
  }

  asm volatile("s_waitcnt vmcnt(0)" ::: "memory");

#pragma unroll
  for (int m = 0; m < 4; ++m) {
    int rbase = row0 + wr * 64 + m * 16 + kgrp * 4;
#pragma unroll
    for (int n = 0; n < 4; ++n) {
      int col = col0 + wc * 64 + n * 16 + lrow;
#pragma unroll
      for (int j = 0; j < 4; ++j) {
        size_t off = (size_t)(rbase + j) * N + col;
        if (OUT_BF16) ((short*)Cp)[off] = f2bf(acc[m][n][j]);
        else          ((float*)Cp)[off] = acc[m][n][j];
      }
    }
  }
}

// ---------------- V transpose: vt[b,h,d,t] <- qkv[b,t, 2C + h*64 + d] ----------------
__global__ __launch_bounds__(256) void transpose_v(const short* __restrict__ qkv,
                                                   short* __restrict__ vt) {
  const int T = 2048;
  __shared__ short sm[64][72];
  const int bh = blockIdx.y, h = bh & 15, b = bh >> 4;
  const int t0 = blockIdx.x * 64;
  const int tid = threadIdx.x;
#pragma unroll
  for (int p = 0; p < 2; ++p) {
    int idx = p * 256 + tid;
    int tl = idx >> 3, d0 = (idx & 7) * 8;
    bf16x8 v = *(const bf16x8*)(qkv + (b * T + t0 + tl) * 3072 + 2048 + h * 64 + d0);
    *(bf16x8*)(&sm[tl][d0]) = v;
  }
  __syncthreads();
#pragma unroll
  for (int p = 0; p < 2; ++p) {
    int idx = p * 256 + tid;
    int d = idx >> 3, ts0 = (idx & 7) * 8;
    bf16x8 o;
#pragma unroll
    for (int j = 0; j < 8; ++j) o[j] = sm[ts0 + j][d];
    *(bf16x8*)(vt + (bh * 64 + d) * T + t0 + ts0) = o;
  }
}

// ---------------- fused attention core step (r13-verified single-chain form) ----------------
template <bool DIAG>
__device__ __forceinline__ void attn_sub(
    const short* __restrict__ Kb, const short* __restrict__ Vb,
    const bf16x8 (&qf)[4], const f32x16& crun,
    f32x16& acc0, f32x16& acc1, float (&den4)[4],
    int l31, int hi, int shalf, int mbits) {
  const int krow = l31 >> 1;
  const int kc0 = (l31 & 1) * 8 + hi;
  const int ss = shalf;
  __builtin_amdgcn_s_setprio(1);
  const bf16x8 kf0 = *(const bf16x8*)(Kb + (ss * 16 + krow) * 128 + (kc0 ^ krow) * 8);
  f32x16 s = MFMA_32x32x16(kf0, qf[0], crun);
#pragma unroll
  for (int kkd = 1; kkd < 4; ++kkd) {
    const bf16x8 kf = *(const bf16x8*)(Kb + (ss * 16 + krow) * 128 +
                                       ((kc0 + kkd * 2) ^ krow) * 8);
    s = MFMA_32x32x16(kf, qf[kkd], s);
  }
  __builtin_amdgcn_s_setprio(0);
  float nm[16];
#pragma unroll
  for (int v = 0; v < 16; ++v) {
    float x = s[v];
    if (DIAG) x = ((mbits >> v) & 1) ? -10000.0f : x;
    float t = fmaf(x, x, 1.0f);
    float num = fmaf(x * __builtin_amdgcn_rsqf(t), 0.5f, 0.5f);
    den4[v & 3] += num;
    nm[v] = num;
  }
#pragma unroll
  for (int k1 = 0; k1 < 2; ++k1) {
    union { uint32_t u[4]; bf16x8 v8; } pu;
#pragma unroll
    for (int w01 = 0; w01 < 2; ++w01) {
      uint32_t c0 = cvt_pk_bf16(nm[2 * w01 + 8 * k1], nm[2 * w01 + 8 * k1 + 1]);
      uint32_t c1 = cvt_pk_bf16(nm[2 * w01 + 8 * k1 + 4], nm[2 * w01 + 8 * k1 + 5]);
      asm volatile("v_permlane32_swap_b32 %0, %1" : "+v"(c0), "+v"(c1));
      pu.u[w01] = c0;
      pu.u[w01 + 2] = c1;
    }
    const int vsw = ((((l31 & 1) * 8) + ss * 4 + k1 * 2 + hi) ^ krow) * 8;
    const bf16x8 vf0 = *(const bf16x8*)(Vb + krow * 128 + vsw);
    const bf16x8 vf1 = *(const bf16x8*)(Vb + (16 + krow) * 128 + vsw);
    __builtin_amdgcn_s_setprio(1);
    acc0 = MFMA_32x32x16(pu.v8, vf0, acc0);
    acc1 = MFMA_32x32x16(pu.v8, vf1, acc1);
    __builtin_amdgcn_s_setprio(0);
  }
}

// grid (8, 158): blockIdx.x = xcd (heads {15-x, x}); blockIdx.y = heavy-first item.
// Items with span >= 18 KV-tiles split into two halves (f32 partials; merged separately).
// Ring-2 double buffer + vmcnt(0) counted wait, single barrier per step, 4 blocks/CU.
__global__ __launch_bounds__(256, 4) void attn_kernel(const short* __restrict__ qkv,
                                                      const short* __restrict__ vt,
                                                      const float* __restrict__ slopes,
                                                      short* __restrict__ attn_out,
                                                      float* __restrict__ partials) {
  const int T = 2048, C = 1024, C3 = 3072;
  __shared__ short Kl[2][4096];
  __shared__ short Vl[2][4096];
  __shared__ float denm[64];

  const int tid = threadIdx.x, wv = tid >> 6, lane = tid & 63;
  const int l31 = lane & 31, hi = lane >> 5;
  const int xcd = blockIdx.x;
  const int by = blockIdx.y;
  const int hA = 15 - xcd;
  const int nSplit = (hA >= 9) ? 15 : 0;         // split qi = 17..31
  const int itemsA = 32 + nSplit;                // per b
  const int totA = 2 * itemsA;
  if (by >= totA + 64) return;

  int h, b, qi, part = -1;
  if (by < totA) {
    h = hA; b = by & 1;
    const int i = by >> 1;
    if (i < 2 * nSplit) { qi = 31 - (i >> 1); part = i & 1; }
    else { qi = 31 - nSplit - (i - 2 * nSplit); }
  } else {
    const int k = by - totA;
    h = xcd; b = k & 1; qi = 31 - (k >> 1);
  }
  const int bh = b * 16 + h;
  const int qsub = wv >> 1, shalf = wv & 1;
  const float slope = slopes[h];
  const float s64 = slope * 64.0f;

  int W = (int)(28.0f / (64.0f * slope)) + 2;
  if (W > 31) W = 31;
  const int kt0f = (qi - W > 0) ? (qi - W) : 0;

  int ktA, ktLim;
  bool hasdiag;
  if (part < 0) { ktA = kt0f; ktLim = qi; hasdiag = true; }
  else {
    const int L = qi - kt0f + 1;
    const int nh = (L + 1) >> 1;
    if (part == 0) { ktA = kt0f; ktLim = kt0f + nh; hasdiag = false; }
    else           { ktA = kt0f + nh; ktLim = qi; hasdiag = true; }
  }
  const int ktMax = hasdiag ? qi : (ktLim - 1);

  int mbits = 0;
#pragma unroll
  for (int v = 0; v < 16; ++v) {
    int s32 = (v & 3) + 8 * (v >> 2) + 4 * hi;
    if (s32 > l31) mbits |= (1 << v);
  }
  int koff[2], voff[2];
#pragma unroll
  for (int p = 0; p < 2; ++p) {
    int idx = p * 256 + tid;
    int rho = idx >> 4, u = idx & 15, c = u ^ (rho & 15);
    koff[p] = (2 * rho + (c >> 3)) * C3 + (c & 7) * 8;
    voff[p] = (2 * rho + (c >> 3)) * T + (c & 7) * 8;
  }
  const short* kbase = qkv + (size_t)b * T * C3 + C + h * 64;
  const short* vbase = vt + (size_t)bh * 64 * T;

  auto STAGE = [&](int bufi, int kt) {
#pragma unroll
    for (int p = 0; p < 2; ++p)
      gload_lds16(kbase + (size_t)kt * 64 * C3 + koff[p], &Kl[bufi][(p * 256 + wv * 64) * 8]);
#pragma unroll
    for (int p = 0; p < 2; ++p)
      gload_lds16(vbase + kt * 64 + voff[p], &Vl[bufi][(p * 256 + wv * 64) * 8]);
  };

  // Q loads FIRST, then pin order, then prologue stage of the first tile
  const int qg = qi * 64 + qsub * 32 + l31;
  bf16x8 qf[4];
#pragma unroll
  for (int ks = 0; ks < 4; ++ks)
    qf[ks] = *(const bf16x8*)(qkv + (size_t)(b * T + qg) * C3 + h * 64 + ks * 16 + hi * 8);
  __builtin_amdgcn_sched_barrier(0);

  STAGE(0, ktA);

  f32x16 crun;
#pragma unroll
  for (int v = 0; v < 16; ++v) {
    int s32 = (v & 3) + 8 * (v >> 2) + 4 * hi;
    crun[v] = slope * (float)(s32 - l31 + 32 * (shalf - qsub) + 64 * (ktA - qi));
  }

  f32x16 acc0 = {}, acc1 = {};
  float den4[4] = {0.f, 0.f, 0.f, 0.f};

  int cA = 0;
  for (int kt = ktA; kt < ktLim; ++kt) {
    asm volatile("s_waitcnt vmcnt(0)" ::: "memory");   // own loads of tile kt landed
    __builtin_amdgcn_s_barrier();                       // all waves: tile kt in LDS, buf cA^1 free
    __builtin_amdgcn_sched_barrier(0);
    STAGE(cA ^ 1, (kt + 1 > ktMax) ? ktMax : kt + 1);
    attn_sub<false>(Kl[cA], Vl[cA], qf, crun, acc0, acc1, den4, l31, hi, shalf, mbits);
#pragma unroll
    for (int v = 0; v < 16; ++v) crun[v] += s64;
    cA ^= 1;
  }
  if (hasdiag) {
    asm volatile("s_waitcnt vmcnt(0)" ::: "memory");
    __builtin_amdgcn_s_barrier();
    if (!(qsub == 0 && shalf == 1)) {
      if (qsub == 1 && shalf == 0)
        attn_sub<false>(Kl[cA], Vl[cA], qf, crun, acc0, acc1, den4, l31, hi, shalf, mbits);
      else
        attn_sub<true>(Kl[cA], Vl[cA], qf, crun, acc0, acc1, den4, l31, hi, shalf, mbits);
    }
  }
  __syncthreads();   // full drain: all in-flight stages landed

  // s-half merge through the non-live buffer
  const int sc = cA ^ 1;
  float den = (den4[0] + den4[1]) + (den4[2] + den4[3]);
  den += __shfl_xor(den, 32);

  if (shalf == 1) {
    float* mp = (float*)(qsub == 0 ? &Kl[sc][0] : &Vl[sc][0]);
#pragma unroll
    for (int i = 0; i < 16; ++i) {
      mp[i * 64 + lane] = acc0[i];
      mp[(16 + i) * 64 + lane] = acc1[i];
    }
    if (hi == 0) denm[qsub * 32 + l31] = den;
  }
  __syncthreads();

  if (shalf == 0) {
    const float* mp = (const float*)(qsub == 0 ? &Kl[sc][0] : &Vl[sc][0]);
    den += denm[qsub * 32 + l31];
#pragma unroll
    for (int i = 0; i < 16; ++i) {
      acc0[i] += mp[i * 64 + lane];
      acc1[i] += mp[(16 + i) * 64 + lane];
    }
    if (part < 0) {
      short* obase = attn_out + (size_t)(b * T + qi * 64 + qsub * 32) * C + h * 64;
#pragma unroll
      for (int v = 0; v < 16; ++v) {
        int ql = (v & 3) + 8 * (v >> 2) + 4 * hi;
        float dv = __int_as_float(__builtin_amdgcn_ds_bpermute(ql << 2, __float_as_int(den)));
        float r = __builtin_amdgcn_rcpf(dv + 1e-6f);
        obase[(size_t)ql * C + l31] = f2bf(acc0[v] * r);
        obase[(size_t)ql * C + 32 + l31] = f2bf(acc1[v] * r);
      }
    } else {
      const int slot = (b * 7 + (h - 9)) * 15 + (qi - 17);
      float* pb = partials + (size_t)slot * 8320 + part * 4160;
#pragma unroll
      for (int v = 0; v < 16; ++v) {
        int ql = (v & 3) + 8 * (v >> 2) + 4 * hi;
        int row = qsub * 32 + ql;
        pb[row * 64 + l31] = acc0[v];
        pb[row * 64 + 32 + l31] = acc1[v];
      }
      if (hi == 0) pb[4096 + qsub * 32 + l31] = den;
    }
  }
}

// ---------------- merge split-tile partials -> bf16 output (exactly 2 addends) ----------------
__global__ __launch_bounds__(256) void attn_merge(const float* __restrict__ partials,
                                                  short* __restrict__ attn_out) {
  const int s = blockIdx.x;            // 210 slots
  const int b = s / 105, r = s % 105;
  const int h = 9 + r / 15, qi = 17 + r % 15;
  const float* p0 = partials + (size_t)s * 8320;
  const float* p1 = p0 + 4160;
  const int t = threadIdx.x;
  const int row = t >> 2, g = (t & 3) * 16;
  const float d = p0[4096 + row] + p1[4096 + row] + 1e-6f;
  const float rd = __builtin_amdgcn_rcpf(d);
  short o[16];
#pragma unroll
  for (int i = 0; i < 16; i += 4) {
    float4 a = *(const float4*)(p0 + row * 64 + g + i);
    float4 c = *(const float4*)(p1 + row * 64 + g + i);
    o[i + 0] = f2bf((a.x + c.x) * rd);
    o[i + 1] = f2bf((a.y + c.y) * rd);
    o[i + 2] = f2bf((a.z + c.z) * rd);
    o[i + 3] = f2bf((a.w + c.w) * rd);
  }
  short* ob = attn_out + ((size_t)(b * 2048 + qi * 64 + row) * 1024 + h * 64 + g);
  *(bf16x8*)ob = *(bf16x8*)&o[0];
  *(bf16x8*)(ob + 8) = *(bf16x8*)&o[8];
}

// ---------------- launcher ----------------
extern "C" void kernel_launch(void* const* d_in, const int* in_sizes, int n_in,
                              void* d_out, int out_size, void* d_ws, size_t ws_size,
                              hipStream_t stream) {
  const float* x      = (const float*)d_in[0];
  const float* w_qkv  = (const float*)d_in[1];
  const float* w_out  = (const float*)d_in[2];
  const float* slopes = (const float*)d_in[3];

  const int B = 2, T = 2048, C = 1024;
  const int M = B * T;        // 4096
  const int N1 = 3 * C;       // 3072

  char* ws = (char*)d_ws;
  short* x_bf    = (short*)(ws);
  short* wqkv_bf = (short*)(ws + 8388608);
  short* wout_bf = (short*)(ws + 14680064);
  short* qkv_bf  = (short*)(ws + 16777216);
  short* vt_bf   = (short*)(ws + 41943040);
  short* ao_bf   = (short*)(ws + 50331648);
  float* partials = (float*)(ws);   // 210 * 8320 * 4 B = 6.99 MB, aliases x_bf (dead after gemm256)

  cast_all<<<4096, 256, 0, stream>>>(x, w_qkv, w_out, x_bf, wqkv_bf, wout_bf);

  gemm256<1><<<dim3((M / 256) * (N1 / 192)), 512, 0, stream>>>(x_bf, wqkv_bf, qkv_bf,
                                                               M, N1, C, N1 / 192);

  transpose_v<<<dim3(T / 64, 32), 256, 0, stream>>>(qkv_bf, vt_bf);

  attn_kernel<<<dim3(8, 158), 256, 0, stream>>>(qkv_bf, vt_bf, slopes, ao_bf, partials);

  attn_merge<<<210, 256, 0, stream>>>(partials, ao_bf);

  gemm_bt128<0><<<dim3(C / 128, M / 128), 256, 0, stream>>>(ao_bf, wout_bf, (float*)d_out, M, C, C);
}

// Round 20
// 95.383 us; speedup vs baseline: 1.0446x; 1.0446x over previous
//
#include <hip/hip_runtime.h>
#include <stdint.h>

typedef __attribute__((ext_vector_type(8))) short bf16x8;
typedef __attribute__((ext_vector_type(4))) float f32x4;
typedef __attribute__((ext_vector_type(16))) float f32x16;

#define MFMA_16x16x32(a, b, c) __builtin_amdgcn_mfma_f32_16x16x32_bf16((a), (b), (c), 0, 0, 0)
#define MFMA_32x32x16(a, b, c) __builtin_amdgcn_mfma_f32_32x32x16_bf16((a), (b), (c), 0, 0, 0)

__device__ __forceinline__ short f2bf(float f) {
  union { float f; uint32_t u; } x;
  x.f = f;
  uint32_t r = x.u + 0x7fffu + ((x.u >> 16) & 1u);
  return (short)(r >> 16);
}

__device__ __forceinline__ uint32_t cvt_pk_bf16(float lo, float hi) {
  uint32_t r;
  asm("v_cvt_pk_bf16_f32 %0, %1, %2" : "=v"(r) : "v"(lo), "v"(hi));
  return r;
}

__device__ __forceinline__ void gload_lds16(const short* g, short* l) {
  __builtin_amdgcn_global_load_lds(
      (const __attribute__((address_space(1))) void*)g,
      (__attribute__((address_space(3))) void*)l, 16, 0, 0);
}

// ---------------- merged cast f32 -> bf16 (Q-rows of w_qkv pre-scaled by 1/8) ----------------
__global__ __launch_bounds__(256) void cast_all(const float* __restrict__ x,
                                                const float* __restrict__ wq,
                                                const float* __restrict__ wo,
                                                short* __restrict__ xb,
                                                short* __restrict__ wqb,
                                                short* __restrict__ wob) {
  int i = blockIdx.x * 256 + threadIdx.x;
  const float* s;
  short* d;
  int off;
  float sc = 1.0f;
  if (i < 524288) { s = x; d = xb; off = i; }
  else if (i < 917504) {
    s = wq; d = wqb; off = i - 524288;
    if (off < 131072) sc = 0.125f;
  }
  else { s = wo; d = wob; off = i - 917504; }
  const float4* sp = (const float4*)s;
  float4 v0 = sp[(size_t)off * 2 + 0];
  float4 v1 = sp[(size_t)off * 2 + 1];
  bf16x8 o;
  o[0] = f2bf(v0.x * sc); o[1] = f2bf(v0.y * sc); o[2] = f2bf(v0.z * sc); o[3] = f2bf(v0.w * sc);
  o[4] = f2bf(v1.x * sc); o[5] = f2bf(v1.y * sc); o[6] = f2bf(v1.z * sc); o[7] = f2bf(v1.w * sc);
  *(bf16x8*)(d + (size_t)off * 8) = o;
}

// ---------------- 256x192 8-phase bf16 GEMM (C = A * B^T form), grid = 256 blocks ----------------
template <int OUT_BF16>
__global__ __launch_bounds__(512, 2) void gemm256(const short* __restrict__ A,
                                                  const short* __restrict__ B,
                                                  void* __restrict__ Cp,
                                                  int M, int N, int K, int ntN) {
  __shared__ short Al[2][2][128 * 64];
  __shared__ short Bl[2][3][64 * 64];

  const int tid = threadIdx.x;
  const int wv = tid >> 6, lane = tid & 63;
  const int wr = wv >> 2, wc = wv & 3;
  const int lrow = lane & 15, kgrp = lane >> 4;
  const int l3 = lrow & 7;
  const int ck0 = ((kgrp ^ l3)) * 8;
  const int ck1 = ((kgrp ^ l3) ^ 4) * 8;

  const int nwg = gridDim.x;
  const int orig = blockIdx.x;
  const int wg = (orig & 7) * (nwg >> 3) + (orig >> 3);
  const int by = wg / ntN, bx = wg % ntN;
  const int row0 = by * 256, col0 = bx * 192;

  const int r_ = tid >> 3;
  const int cs_ = ((tid & 7) ^ (r_ & 7)) * 8;

  const int NT = K >> 6;
  const int NI = NT >> 1;
  const int NTm1 = NT - 1;

  auto stgA = [&](int slot, int h, int j, int kt) {
    gload_lds16(A + (size_t)(row0 + h * 128 + j * 64 + r_) * K + kt * 64 + cs_,
                &Al[slot][h][j * 4096 + wv * 512]);
  };
  auto stgB = [&](int slot, int j, int kt) {
    gload_lds16(B + (size_t)(col0 + j * 64 + r_) * K + kt * 64 + cs_,
                &Bl[slot][j][wv * 512]);
  };

  f32x4 acc[8][3] = {};

  stgB(0, 0, 0); stgB(0, 1, 0); stgB(0, 2, 0);
  stgA(0, 0, 0, 0); stgA(0, 0, 1, 0); stgA(0, 1, 0, 0); stgA(0, 1, 1, 0);
  stgB(1, 0, 1); stgB(1, 1, 1); stgB(1, 2, 1);
  asm volatile("s_waitcnt vmcnt(3)" ::: "memory");
  __builtin_amdgcn_s_barrier();

  for (int i = 0; i < NI; ++i) {
    const int ktB1 = (2 * i + 1);
    const int ktP2 = (2 * i + 2 > NTm1) ? NTm1 : 2 * i + 2;
    const int ktP3 = (2 * i + 3 > NTm1) ? NTm1 : 2 * i + 3;
#pragma unroll
    for (int s = 0; s < 2; ++s) {
      bf16x8 bfr[3][2];
#pragma unroll
      for (int q = 0; q < 4; ++q) {
        if (q == 0) {
#pragma unroll
          for (int n = 0; n < 3; ++n) {
            const int row = wc * 48 + n * 16 + lrow;
            const int th = row >> 6;
            const int lr = row & 63;
            bfr[n][0] = *(const bf16x8*)(&Bl[s][th][lr * 64 + ck0]);
            bfr[n][1] = *(const bf16x8*)(&Bl[s][th][lr * 64 + ck1]);
          }
        }
        bf16x8 afr[2][2];
#pragma unroll
        for (int mm = 0; mm < 2; ++mm) {
          const int m = q * 2 + mm;
          afr[mm][0] = *(const bf16x8*)(&Al[s][wr][lrow * 64 + m * 1024 + ck0]);
          afr[mm][1] = *(const bf16x8*)(&Al[s][wr][lrow * 64 + m * 1024 + ck1]);
        }
        if (s == 0) {
          if (q == 0) { stgA(1, 0, 0, ktB1); stgA(1, 0, 1, ktB1); stgA(1, 1, 0, ktB1); stgA(1, 1, 1, ktB1); }
          else if (q == 1) { stgB(0, 0, ktP2); stgB(0, 1, ktP2); }
          else if (q == 2) { stgB(0, 2, ktP2); }
        } else {
          if (q == 0) { stgA(0, 0, 0, ktP2); stgA(0, 0, 1, ktP2); stgA(0, 1, 0, ktP2); stgA(0, 1, 1, ktP2); }
          else if (q == 1) { stgB(1, 0, ktP3); stgB(1, 1, ktP3); }
          else if (q == 2) { stgB(1, 2, ktP3); }
        }
        __builtin_amdgcn_sched_barrier(0);
        __builtin_amdgcn_s_barrier();
        asm volatile("s_waitcnt lgkmcnt(0)" ::: "memory");
        __builtin_amdgcn_sched_barrier(0);
        __builtin_amdgcn_s_setprio(1);
#pragma unroll
        for (int mm = 0; mm < 2; ++mm)
#pragma unroll
          for (int n = 0; n < 3; ++n)
#pragma unroll
            for (int kk = 0; kk < 2; ++kk)
              acc[q * 2 + mm][n] = MFMA_16x16x32(afr[mm][kk], bfr[n][kk], acc[q * 2 + mm][n]);
        __builtin_amdgcn_s_setprio(0);
        __builtin_amdgcn_sched_barrier(0);
        if (q == 3) {
          asm volatile("s_waitcnt vmcnt(3)" ::: "memory");
        }
        __builtin_amdgcn_s_barrier();
      }
    }
  }

  asm volatile("s_waitcnt vmcnt(0)" ::: "memory");

#pragma unroll
  for (int m = 0; m < 8; ++m) {
    const int grow = row0 + wr * 128 + m * 16 + kgrp * 4;
#pragma unroll
    for (int n = 0; n < 3; ++n) {
      const int gcol = col0 + wc * 48 + n * 16 + lrow;
#pragma unroll
      for (int j = 0; j < 4; ++j) {
        const size_t off = (size_t)(grow + j) * N + gcol;
        if (OUT_BF16) ((short*)Cp)[off] = f2bf(acc[m][n][j]);
        else          ((float*)Cp)[off] = acc[m][n][j];
      }
    }
  }
}

// ---------------- 64x128 bf16 GEMM (output GEMM), dbuf + single barrier + vmcnt(6) ----------------
template <int OUT_BF16>
__global__ __launch_bounds__(256, 4) void gemm_bt64(const short* __restrict__ A,
                                                    const short* __restrict__ B,
                                                    void* __restrict__ Cp,
                                                    int M, int N, int K) {
  __shared__ short As[2][64 * 64];
  __shared__ short Bs[2][128 * 64];
  const int tid = threadIdx.x;
  const int wave = tid >> 6, lane = tid & 63;
  const int wr = wave >> 1, wc = wave & 1;
  const int row0 = blockIdx.y * 64, col0 = blockIdx.x * 128;
  const int lrow = lane & 15;
  const int kgrp = lane >> 4;
  const int l3 = lrow & 7;

  const int r_ = tid >> 3;
  const int cs_ = ((tid & 7) ^ (r_ & 7)) * 8;

  const int NT = K >> 6;

  auto STG = [&](int buf, int kt) {
#pragma unroll
    for (int it = 0; it < 2; ++it)
      gload_lds16(A + (size_t)(row0 + it * 32 + r_) * K + kt * 64 + cs_,
                  &As[buf][(it * 256 + wave * 64) * 8]);
#pragma unroll
    for (int it = 0; it < 4; ++it)
      gload_lds16(B + (size_t)(col0 + it * 32 + r_) * K + kt * 64 + cs_,
                  &Bs[buf][(it * 256 + wave * 64) * 8]);
  };

  f32x4 acc[2][4] = {};

  STG(0, 0);

  for (int kt = 0; kt < NT; ++kt) {
    __builtin_amdgcn_s_barrier();
    __builtin_amdgcn_sched_barrier(0);
    const int ktn = (kt + 1 >= NT) ? NT - 1 : kt + 1;
    STG((kt + 1) & 1, ktn);
    asm volatile("s_waitcnt vmcnt(6)" ::: "memory");
    __builtin_amdgcn_sched_barrier(0);
    const short* Ab = As[kt & 1];
    const short* Bb = Bs[kt & 1];
#pragma unroll
    for (int kk = 0; kk < 2; ++kk) {
      const int ck = ((kk * 4 + kgrp) ^ l3) * 8;
      bf16x8 a[2], b[4];
#pragma unroll
      for (int m = 0; m < 2; ++m)
        a[m] = *(const bf16x8*)(Ab + (wr * 32 + m * 16 + lrow) * 64 + ck);
#pragma unroll
      for (int n = 0; n < 4; ++n)
        b[n] = *(const bf16x8*)(Bb + (wc * 64 + n * 16 + lrow) * 64 + ck);
#pragma unroll
      for (int m = 0; m < 2; ++m)
#pragma unroll
        for (int n = 0; n < 4; ++n)
          acc[m][n] = MFMA_16x16x32(a[m], b[n], acc[m][n]);
    }
  }

  asm volatile("s_waitcnt vmcnt(0)" ::: "memory");

#pragma unroll
  for (int m = 0; m < 2; ++m) {
    int rbase = row0 + wr * 32 + m * 16 + kgrp * 4;
#pragma unroll
    for (int n = 0; n < 4; ++n) {
      int col = col0 + wc * 64 + n * 16 + lrow;
#pragma unroll
      for (int j = 0; j < 4; ++j) {
        size_t off = (size_t)(rbase + j) * N + col;
        if (OUT_BF16) ((short*)Cp)[off] = f2bf(acc[m][n][j]);
        else          ((float*)Cp)[off] = acc[m][n][j];
      }
    }
  }
}

// ---------------- V transpose: vt[b,h,d,t] <- qkv[b,t, 2C + h*64 + d] ----------------
__global__ __launch_bounds__(256) void transpose_v(const short* __restrict__ qkv,
                                                   short* __restrict__ vt) {
  const int T = 2048;
  __shared__ short sm[64][72];
  const int bh = blockIdx.y, h = bh & 15, b = bh >> 4;
  const int t0 = blockIdx.x * 64;
  const int tid = threadIdx.x;
#pragma unroll
  for (int p = 0; p < 2; ++p) {
    int idx = p * 256 + tid;
    int tl = idx >> 3, d0 = (idx & 7) * 8;
    bf16x8 v = *(const bf16x8*)(qkv + (b * T + t0 + tl) * 3072 + 2048 + h * 64 + d0);
    *(bf16x8*)(&sm[tl][d0]) = v;
  }
  __syncthreads();
#pragma unroll
  for (int p = 0; p < 2; ++p) {
    int idx = p * 256 + tid;
    int d = idx >> 3, ts0 = (idx & 7) * 8;
    bf16x8 o;
#pragma unroll
    for (int j = 0; j < 8; ++j) o[j] = sm[ts0 + j][d];
    *(bf16x8*)(vt + (bh * 64 + d) * T + t0 + ts0) = o;
  }
}

// ---------------- fused attention core step (r13-verified single-chain form) ----------------
template <bool DIAG>
__device__ __forceinline__ void attn_sub(
    const short* __restrict__ Kb, const short* __restrict__ Vb,
    const bf16x8 (&qf)[4], const f32x16& crun,
    f32x16& acc0, f32x16& acc1, float (&den4)[4],
    int l31, int hi, int shalf, int mbits) {
  const int krow = l31 >> 1;
  const int kc0 = (l31 & 1) * 8 + hi;
  const int ss = shalf;
  __builtin_amdgcn_s_setprio(1);
  const bf16x8 kf0 = *(const bf16x8*)(Kb + (ss * 16 + krow) * 128 + (kc0 ^ krow) * 8);
  f32x16 s = MFMA_32x32x16(kf0, qf[0], crun);
#pragma unroll
  for (int kkd = 1; kkd < 4; ++kkd) {
    const bf16x8 kf = *(const bf16x8*)(Kb + (ss * 16 + krow) * 128 +
                                       ((kc0 + kkd * 2) ^ krow) * 8);
    s = MFMA_32x32x16(kf, qf[kkd], s);
  }
  __builtin_amdgcn_s_setprio(0);
  float nm[16];
#pragma unroll
  for (int v = 0; v < 16; ++v) {
    float x = s[v];
    if (DIAG) x = ((mbits >> v) & 1) ? -10000.0f : x;
    float t = fmaf(x, x, 1.0f);
    float num = fmaf(x * __builtin_amdgcn_rsqf(t), 0.5f, 0.5f);
    den4[v & 3] += num;
    nm[v] = num;
  }
#pragma unroll
  for (int k1 = 0; k1 < 2; ++k1) {
    union { uint32_t u[4]; bf16x8 v8; } pu;
#pragma unroll
    for (int w01 = 0; w01 < 2; ++w01) {
      uint32_t c0 = cvt_pk_bf16(nm[2 * w01 + 8 * k1], nm[2 * w01 + 8 * k1 + 1]);
      uint32_t c1 = cvt_pk_bf16(nm[2 * w01 + 8 * k1 + 4], nm[2 * w01 + 8 * k1 + 5]);
      asm volatile("v_permlane32_swap_b32 %0, %1" : "+v"(c0), "+v"(c1));
      pu.u[w01] = c0;
      pu.u[w01 + 2] = c1;
    }
    const int vsw = ((((l31 & 1) * 8) + ss * 4 + k1 * 2 + hi) ^ krow) * 8;
    const bf16x8 vf0 = *(const bf16x8*)(Vb + krow * 128 + vsw);
    const bf16x8 vf1 = *(const bf16x8*)(Vb + (16 + krow) * 128 + vsw);
    __builtin_amdgcn_s_setprio(1);
    acc0 = MFMA_32x32x16(pu.v8, vf0, acc0);
    acc1 = MFMA_32x32x16(pu.v8, vf1, acc1);
    __builtin_amdgcn_s_setprio(0);
  }
}

// grid (8, 158): blockIdx.x = xcd (heads {15-x, x}); blockIdx.y = heavy-first item.
// Items with span >= 18 KV-tiles split into two halves (f32 partials; merged separately).
// Ring-2 double buffer + vmcnt(0) counted wait, single barrier per step, 4 blocks/CU.
__global__ __launch_bounds__(256, 4) void attn_kernel(const short* __restrict__ qkv,
                                                      const short* __restrict__ vt,
                                                      const float* __restrict__ slopes,
                                                      short* __restrict__ attn_out,
                                                      float* __restrict__ partials) {
  const int T = 2048, C = 1024, C3 = 3072;
  __shared__ short Kl[2][4096];
  __shared__ short Vl[2][4096];
  __shared__ float denm[64];

  const int tid = threadIdx.x, wv = tid >> 6, lane = tid & 63;
  const int l31 = lane & 31, hi = lane >> 5;
  const int xcd = blockIdx.x;
  const int by = blockIdx.y;
  const int hA = 15 - xcd;
  const int nSplit = (hA >= 9) ? 15 : 0;         // split qi = 17..31
  const int itemsA = 32 + nSplit;                // per b
  const int totA = 2 * itemsA;
  if (by >= totA + 64) return;

  int h, b, qi, part = -1;
  if (by < totA) {
    h = hA; b = by & 1;
    const int i = by >> 1;
    if (i < 2 * nSplit) { qi = 31 - (i >> 1); part = i & 1; }
    else { qi = 31 - nSplit - (i - 2 * nSplit); }
  } else {
    const int k = by - totA;
    h = xcd; b = k & 1; qi = 31 - (k >> 1);
  }
  const int bh = b * 16 + h;
  const int qsub = wv >> 1, shalf = wv & 1;
  const float slope = slopes[h];
  const float s64 = slope * 64.0f;

  int W = (int)(28.0f / (64.0f * slope)) + 2;
  if (W > 31) W = 31;
  const int kt0f = (qi - W > 0) ? (qi - W) : 0;

  int ktA, ktLim;
  bool hasdiag;
  if (part < 0) { ktA = kt0f; ktLim = qi; hasdiag = true; }
  else {
    const int L = qi - kt0f + 1;
    const int nh = (L + 1) >> 1;
    if (part == 0) { ktA = kt0f; ktLim = kt0f + nh; hasdiag = false; }
    else           { ktA = kt0f + nh; ktLim = qi; hasdiag = true; }
  }
  const int ktMax = hasdiag ? qi : (ktLim - 1);

  int mbits = 0;
#pragma unroll
  for (int v = 0; v < 16; ++v) {
    int s32 = (v & 3) + 8 * (v >> 2) + 4 * hi;
    if (s32 > l31) mbits |= (1 << v);
  }
  int koff[2], voff[2];
#pragma unroll
  for (int p = 0; p < 2; ++p) {
    int idx = p * 256 + tid;
    int rho = idx >> 4, u = idx & 15, c = u ^ (rho & 15);
    koff[p] = (2 * rho + (c >> 3)) * C3 + (c & 7) * 8;
    voff[p] = (2 * rho + (c >> 3)) * T + (c & 7) * 8;
  }
  const short* kbase = qkv + (size_t)b * T * C3 + C + h * 64;
  const short* vbase = vt + (size_t)bh * 64 * T;

  auto STAGE = [&](int bufi, int kt) {
#pragma unroll
    for (int p = 0; p < 2; ++p)
      gload_lds16(kbase + (size_t)kt * 64 * C3 + koff[p], &Kl[bufi][(p * 256 + wv * 64) * 8]);
#pragma unroll
    for (int p = 0; p < 2; ++p)
      gload_lds16(vbase + kt * 64 + voff[p], &Vl[bufi][(p * 256 + wv * 64) * 8]);
  };

  // Q loads FIRST, then pin order, then prologue stage of the first tile
  const int qg = qi * 64 + qsub * 32 + l31;
  bf16x8 qf[4];
#pragma unroll
  for (int ks = 0; ks < 4; ++ks)
    qf[ks] = *(const bf16x8*)(qkv + (size_t)(b * T + qg) * C3 + h * 64 + ks * 16 + hi * 8);
  __builtin_amdgcn_sched_barrier(0);

  STAGE(0, ktA);

  f32x16 crun;
#pragma unroll
  for (int v = 0; v < 16; ++v) {
    int s32 = (v & 3) + 8 * (v >> 2) + 4 * hi;
    crun[v] = slope * (float)(s32 - l31 + 32 * (shalf - qsub) + 64 * (ktA - qi));
  }

  f32x16 acc0 = {}, acc1 = {};
  float den4[4] = {0.f, 0.f, 0.f, 0.f};

  int cA = 0;
  for (int kt = ktA; kt < ktLim; ++kt) {
    asm volatile("s_waitcnt vmcnt(0)" ::: "memory");   // own loads of tile kt landed
    __builtin_amdgcn_s_barrier();                       // all waves: tile kt in LDS, buf cA^1 free
    __builtin_amdgcn_sched_barrier(0);
    STAGE(cA ^ 1, (kt + 1 > ktMax) ? ktMax : kt + 1);
    attn_sub<false>(Kl[cA], Vl[cA], qf, crun, acc0, acc1, den4, l31, hi, shalf, mbits);
#pragma unroll
    for (int v = 0; v < 16; ++v) crun[v] += s64;
    cA ^= 1;
  }
  if (hasdiag) {
    asm volatile("s_waitcnt vmcnt(0)" ::: "memory");
    __builtin_amdgcn_s_barrier();
    if (!(qsub == 0 && shalf == 1)) {
      if (qsub == 1 && shalf == 0)
        attn_sub<false>(Kl[cA], Vl[cA], qf, crun, acc0, acc1, den4, l31, hi, shalf, mbits);
      else
        attn_sub<true>(Kl[cA], Vl[cA], qf, crun, acc0, acc1, den4, l31, hi, shalf, mbits);
    }
  }
  __syncthreads();   // full drain: all in-flight stages landed

  // s-half merge through the non-live buffer
  const int sc = cA ^ 1;
  float den = (den4[0] + den4[1]) + (den4[2] + den4[3]);
  den += __shfl_xor(den, 32);

  if (shalf == 1) {
    float* mp = (float*)(qsub == 0 ? &Kl[sc][0] : &Vl[sc][0]);
#pragma unroll
    for (int i = 0; i < 16; ++i) {
      mp[i * 64 + lane] = acc0[i];
      mp[(16 + i) * 64 + lane] = acc1[i];
    }
    if (hi == 0) denm[qsub * 32 + l31] = den;
  }
  __syncthreads();

  if (shalf == 0) {
    const float* mp = (const float*)(qsub == 0 ? &Kl[sc][0] : &Vl[sc][0]);
    den += denm[qsub * 32 + l31];
#pragma unroll
    for (int i = 0; i < 16; ++i) {
      acc0[i] += mp[i * 64 + lane];
      acc1[i] += mp[(16 + i) * 64 + lane];
    }
    if (part < 0) {
      short* obase = attn_out + (size_t)(b * T + qi * 64 + qsub * 32) * C + h * 64;
#pragma unroll
      for (int v = 0; v < 16; ++v) {
        int ql = (v & 3) + 8 * (v >> 2) + 4 * hi;
        float dv = __int_as_float(__builtin_amdgcn_ds_bpermute(ql << 2, __float_as_int(den)));
        float r = __builtin_amdgcn_rcpf(dv + 1e-6f);
        obase[(size_t)ql * C + l31] = f2bf(acc0[v] * r);
        obase[(size_t)ql * C + 32 + l31] = f2bf(acc1[v] * r);
      }
    } else {
      const int slot = (b * 7 + (h - 9)) * 15 + (qi - 17);
      float* pb = partials + (size_t)slot * 8320 + part * 4160;
#pragma unroll
      for (int v = 0; v < 16; ++v) {
        int ql = (v & 3) + 8 * (v >> 2) + 4 * hi;
        int row = qsub * 32 + ql;
        pb[row * 64 + l31] = acc0[v];
        pb[row * 64 + 32 + l31] = acc1[v];
      }
      if (hi == 0) pb[4096 + qsub * 32 + l31] = den;
    }
  }
}

// ---------------- merge split-tile partials -> bf16 output (exactly 2 addends) ----------------
__global__ __launch_bounds__(256) void attn_merge(const float* __restrict__ partials,
                                                  short* __restrict__ attn_out) {
  const int s = blockIdx.x;            // 210 slots
  const int b = s / 105, r = s % 105;
  const int h = 9 + r / 15, qi = 17 + r % 15;
  const float* p0 = partials + (size_t)s * 8320;
  const float* p1 = p0 + 4160;
  const int t = threadIdx.x;
  const int row = t >> 2, g = (t & 3) * 16;
  const float d = p0[4096 + row] + p1[4096 + row] + 1e-6f;
  const float rd = __builtin_amdgcn_rcpf(d);
  short o[16];
#pragma unroll
  for (int i = 0; i < 16; i += 4) {
    float4 a = *(const float4*)(p0 + row * 64 + g + i);
    float4 c = *(const float4*)(p1 + row * 64 + g + i);
    o[i + 0] = f2bf((a.x + c.x) * rd);
    o[i + 1] = f2bf((a.y + c.y) * rd);
    o[i + 2] = f2bf((a.z + c.z) * rd);
    o[i + 3] = f2bf((a.w + c.w) * rd);
  }
  short* ob = attn_out + ((size_t)(b * 2048 + qi * 64 + row) * 1024 + h * 64 + g);
  *(bf16x8*)ob = *(bf16x8*)&o[0];
  *(bf16x8*)(ob + 8) = *(bf16x8*)&o[8];
}

// ---------------- launcher ----------------
extern "C" void kernel_launch(void* const* d_in, const int* in_sizes, int n_in,
                              void* d_out, int out_size, void* d_ws, size_t ws_size,
                              hipStream_t stream) {
  const float* x      = (const float*)d_in[0];
  const float* w_qkv  = (const float*)d_in[1];
  const float* w_out  = (const float*)d_in[2];
  const float* slopes = (const float*)d_in[3];

  const int B = 2, T = 2048, C = 1024;
  const int M = B * T;        // 4096
  const int N1 = 3 * C;       // 3072

  char* ws = (char*)d_ws;
  short* x_bf    = (short*)(ws);
  short* wqkv_bf = (short*)(ws + 8388608);
  short* wout_bf = (short*)(ws + 14680064);
  short* qkv_bf  = (short*)(ws + 16777216);
  short* vt_bf   = (short*)(ws + 41943040);
  short* ao_bf   = (short*)(ws + 50331648);
  float* partials = (float*)(ws);   // 210 * 8320 * 4 B = 6.99 MB, aliases x_bf (dead after gemm256)

  cast_all<<<4096, 256, 0, stream>>>(x, w_qkv, w_out, x_bf, wqkv_bf, wout_bf);

  gemm256<1><<<dim3((M / 256) * (N1 / 192)), 512, 0, stream>>>(x_bf, wqkv_bf, qkv_bf,
                                                               M, N1, C, N1 / 192);

  transpose_v<<<dim3(T / 64, 32), 256, 0, stream>>>(qkv_bf, vt_bf);

  attn_kernel<<<dim3(8, 158), 256, 0, stream>>>(qkv_bf, vt_bf, slopes, ao_bf, partials);

  attn_merge<<<210, 256, 0, stream>>>(partials, ao_bf);

  gemm_bt64<0><<<dim3(C / 128, M / 64), 256, 0, stream>>>(ao_bf, wout_bf, (float*)d_out, M, C, C);
}